// Round 11
// baseline (490.023 us; speedup 1.0000x reference)
//
#include <hip/hip_runtime.h>
#include <hip/hip_bf16.h>
#include <math.h>

#define HDIM 1024
#define NB 32
#define LA 2048
#define LO 32

typedef __attribute__((ext_vector_type(8))) short bf16x8;
typedef __attribute__((ext_vector_type(4))) float f32x4;
typedef unsigned int u32;

__device__ __forceinline__ float tanh_fast(float x){
    return 2.0f / (1.0f + __expf(-2.0f * x)) - 1.0f;
}

__device__ __forceinline__ void load_lds16(const void* gptr, void* lptr){
    __builtin_amdgcn_global_load_lds(
        (const __attribute__((address_space(1))) u32*)gptr,
        (__attribute__((address_space(3))) u32*)lptr, 16, 0, 0);
}

__global__ void zero_kernel(float* __restrict__ p, int n){
    int i = blockIdx.x * blockDim.x + threadIdx.x;
    int stride = gridDim.x * blockDim.x;
    for (; i < n; i += stride) p[i] = 0.0f;
}

__global__ void conv_bf16_kernel(const float* __restrict__ in, __hip_bfloat16* __restrict__ out, long n){
    long i = ((long)blockIdx.x * blockDim.x + threadIdx.x) * 4;
    long stride = (long)gridDim.x * blockDim.x * 4;
    for (; i < n; i += stride){
        float4 v = *(const float4*)(in + i);
        union { __hip_bfloat16 h[4]; short4 s; } u;
        u.h[0] = __float2bfloat16(v.x); u.h[1] = __float2bfloat16(v.y);
        u.h[2] = __float2bfloat16(v.z); u.h[3] = __float2bfloat16(v.w);
        *(short4*)(out + i) = u.s;
    }
}

__global__ void gather_kernel(const float* __restrict__ qc, const int* __restrict__ ans,
                              float* __restrict__ oqc){
    int b = blockIdx.x, tid = threadIdx.x;
    int idx = ans[b];
    const float* src = qc + ((size_t)b * 64 + idx) * HDIM;
    float* dst = oqc + (size_t)b * HDIM;
    #pragma unroll
    for (int l = 0; l < 4; l++) dst[tid + l * 256] = src[tid + l * 256];
}

// out[g,h] = bias[h] + dot(in[g,:], W[h,:])   grid (G, 16), block 256 (4 waves).
__global__ __launch_bounds__(256) void proj_kernel(
    const float* __restrict__ in, const float* __restrict__ W,
    const float* __restrict__ bias, float* __restrict__ out){
    __shared__ float xin[HDIM];
    const int g = blockIdx.x, tid = threadIdx.x;
    const int lane = tid & 63, wave = tid >> 6;
    *(float4*)&xin[tid * 4] = *(const float4*)&in[(size_t)g * HDIM + tid * 4];
    __syncthreads();
    float4 xv[4];
    #pragma unroll
    for (int c = 0; c < 4; c++) xv[c] = *(const float4*)&xin[(c * 64 + lane) * 4];
    const int hbase = blockIdx.y * 64 + wave * 16;
    #pragma unroll 4
    for (int r = 0; r < 16; r++){
        int h = hbase + r;
        const float* Wr = W + (size_t)h * HDIM;
        float p = 0.f;
        #pragma unroll
        for (int c = 0; c < 4; c++){
            float4 wv = *(const float4*)&Wr[(c * 64 + lane) * 4];
            p = fmaf(xv[c].x, wv.x, p); p = fmaf(xv[c].y, wv.y, p);
            p = fmaf(xv[c].z, wv.z, p); p = fmaf(xv[c].w, wv.w, p);
        }
        #pragma unroll
        for (int off = 1; off < 64; off <<= 1) p += __shfl_xor(p, off, 64);
        if (lane == 0) out[(size_t)g * HDIM + h] = p + bias[h];
    }
}

// ---------------- 128h x 256a article score kernel, f32 B reg-staging ---------
// C[h, article] = Kw-bf16 (A, global_load_lds) x article-f32 (B, reg-staged with
// in-kernel f32->bf16 cvt + swizzled ds_write). 8 waves of 64h x 64a. BK=32.
// LDS: 2 bufs x {A 8KB, B 16KB} = 48 KB -> 2 blocks/CU. 2-barrier double buffer:
// issue A + load B regs BEFORE COMPUTE (latency hidden under MFMA), cvt+write
// after, vmcnt(0)+syncthreads per tile. Eliminates the article bf16 pre-pass.
// Swizzle byte ^= ((rw>>1)&3)<<4; A = inverse-swizzled source (m201 rule), B =
// direct swizzled ds_write; reads swizzled on both. XCD decode needs na%8==0.
#define NT 32   // K tiles = 1024/32
__global__ __launch_bounds__(512, 4) void score_mfma_f32b(
    const float* __restrict__ Xf, const __hip_bfloat16* __restrict__ Kw,
    const float* __restrict__ Kb, const float* __restrict__ Qp,
    const float* __restrict__ vw, float* __restrict__ s,
    int rows_per_batch)
{
    // buf0: A [0,8K) B [8K,24K); buf1 at 24K.
    __shared__ __align__(16) char lds[49152];
    const int tid = threadIdx.x;
    const int lane = tid & 63, wid = tid >> 6;
    const int wm = wid >> 2, wn = wid & 3;
    const int lr = lane & 15, lg = lane >> 4;

    const int na = gridDim.x >> 3;          // article tiles of 256 rows
    const int bid = blockIdx.x;
    const int xcd = bid & 7, seq = bid >> 3;
    const int a_idx = xcd * (na >> 3) + (seq >> 3);
    const int h_idx = seq & 7;              // 8 h-tiles of 128
    const int a0 = a_idx * 256, h0 = h_idx * 128;

    f32x4 acc[4][4] = {};

    // ---- A staging: global_load_lds, inverse-swizzled source, +64B/tile ----
    const int rA = tid >> 2;                              // 0..127
    const int srcbA = ((tid & 3) * 16) ^ (((rA >> 1) & 3) << 4);
    const char* pA = (const char*)Kw + (size_t)(h0 + rA) * 2048 + srcbA;
    char* dA = lds + tid * 16;

    // ---- B staging: f32 regs -> cvt -> swizzled ds_write (32B bf16/thread) ----
    const int rB = tid >> 1;                              // 0..255
    const int hb = tid & 1;                               // 16-float half
    const float* pB = Xf + (size_t)(a0 + rB) * HDIM + hb * 16;
    const int swzB = ((rB >> 1) & 3) << 4;
    char* dB0 = lds + 8192 + rB * 64 + ((hb * 32) ^ swzB);
    char* dB1 = lds + 8192 + rB * 64 + ((hb * 32 + 16) ^ swzB);

    // ---- swizzled LDS read offsets ----
    int aoff[4], boff[4];
    #pragma unroll
    for (int hf = 0; hf < 4; hf++){
        int rw = wm * 64 + hf * 16 + lr;
        aoff[hf] = rw * 64 + ((lg * 16) ^ (((rw >> 1) & 3) << 4));
    }
    #pragma unroll
    for (int af = 0; af < 4; af++){
        int rw = wn * 64 + af * 16 + lr;
        boff[af] = 8192 + rw * 64 + ((lg * 16) ^ (((rw >> 1) & 3) << 4));
    }

    float4 br0, br1, br2, br3;
#define LOADB(kt) do { const float* q = pB + (kt) * 32; \
    br0 = *(const float4*)q; br1 = *(const float4*)(q + 4); \
    br2 = *(const float4*)(q + 8); br3 = *(const float4*)(q + 12); } while(0)
#define CVTWRITE(bufoff) do { \
    union { __hip_bfloat16 h[8]; bf16x8 v; } u0, u1; \
    u0.h[0]=__float2bfloat16(br0.x); u0.h[1]=__float2bfloat16(br0.y); \
    u0.h[2]=__float2bfloat16(br0.z); u0.h[3]=__float2bfloat16(br0.w); \
    u0.h[4]=__float2bfloat16(br1.x); u0.h[5]=__float2bfloat16(br1.y); \
    u0.h[6]=__float2bfloat16(br1.z); u0.h[7]=__float2bfloat16(br1.w); \
    u1.h[0]=__float2bfloat16(br2.x); u1.h[1]=__float2bfloat16(br2.y); \
    u1.h[2]=__float2bfloat16(br2.z); u1.h[3]=__float2bfloat16(br2.w); \
    u1.h[4]=__float2bfloat16(br3.x); u1.h[5]=__float2bfloat16(br3.y); \
    u1.h[6]=__float2bfloat16(br3.z); u1.h[7]=__float2bfloat16(br3.w); \
    *(bf16x8*)(dB0 + (bufoff)) = u0.v; \
    *(bf16x8*)(dB1 + (bufoff)) = u1.v; } while(0)
#define ISSUEA(kt, bufoff) load_lds16(pA + (size_t)(kt) * 64, dA + (bufoff))
#define COMPUTE(bufoff) do { \
    bf16x8 av[4], bv[4]; \
    _Pragma("unroll") \
    for (int hf = 0; hf < 4; hf++) av[hf] = *(const bf16x8*)(lds + (bufoff) + aoff[hf]); \
    _Pragma("unroll") \
    for (int af = 0; af < 4; af++) bv[af] = *(const bf16x8*)(lds + (bufoff) + boff[af]); \
    __builtin_amdgcn_s_setprio(1); \
    _Pragma("unroll") \
    for (int hf = 0; hf < 4; hf++) \
        _Pragma("unroll") \
        for (int af = 0; af < 4; af++) \
            acc[hf][af] = __builtin_amdgcn_mfma_f32_16x16x32_bf16(av[hf], bv[af], acc[hf][af], 0, 0, 0); \
    __builtin_amdgcn_s_setprio(0); } while(0)

    // prologue: tile 0 into buf0
    ISSUEA(0, 0);
    LOADB(0);
    CVTWRITE(0);
    asm volatile("s_waitcnt vmcnt(0)" ::: "memory");
    __syncthreads();

    int bo = 0;
    for (int t = 0; t < NT; ++t){
        if (t < NT - 1){
            ISSUEA(t + 1, bo ^ 24576);
            LOADB(t + 1);
        }
        COMPUTE(bo);
        if (t < NT - 1){
            CVTWRITE(bo ^ 24576);
            asm volatile("s_waitcnt vmcnt(0)" ::: "memory");
        }
        __syncthreads();
        bo ^= 24576;
    }

    // epilogue: C col (article) = lr within frag af; C rows (h) = lg*4+r in frag hf
    const int b = a0 / rows_per_batch;  // uniform: 256 | 2048
    float qv[4][4], vv[4][4];
    #pragma unroll
    for (int hf = 0; hf < 4; hf++){
        int hbase = h0 + wm * 64 + hf * 16 + lg * 4;
        float4 kb4 = *(const float4*)(Kb + hbase);
        float4 qp4 = *(const float4*)(Qp + (size_t)b * HDIM + hbase);
        float4 vw4 = *(const float4*)(vw + hbase);
        qv[hf][0] = kb4.x + qp4.x; qv[hf][1] = kb4.y + qp4.y;
        qv[hf][2] = kb4.z + qp4.z; qv[hf][3] = kb4.w + qp4.w;
        vv[hf][0] = vw4.x; vv[hf][1] = vw4.y; vv[hf][2] = vw4.z; vv[hf][3] = vw4.w;
    }
    #pragma unroll
    for (int af = 0; af < 4; af++){
        float sacc = 0.f;
        #pragma unroll
        for (int hf = 0; hf < 4; hf++)
            #pragma unroll
            for (int r = 0; r < 4; r++)
                sacc += tanh_fast(acc[hf][af][r] + qv[hf][r]) * vv[hf][r];
        sacc += __shfl_xor(sacc, 16, 64);
        sacc += __shfl_xor(sacc, 32, 64);
        if (lane < 16)
            atomicAdd(&s[a0 + wn * 64 + af * 16 + lr], sacc);
    }
#undef LOADB
#undef CVTWRITE
#undef ISSUEA
#undef COMPUTE
}

// ---------------- old 128x128 4-wave score kernel (option path) --------------
#define SBM 128
#define SBN 128
__global__ __launch_bounds__(256) void score_mfma_kernel(
    const __hip_bfloat16* __restrict__ X, const __hip_bfloat16* __restrict__ Kw,
    const float* __restrict__ Kb, const float* __restrict__ Qp,
    const float* __restrict__ vw, float* __restrict__ s,
    int row_off, int rows_per_batch)
{
    __shared__ __align__(16) __hip_bfloat16 As[SBM][32];
    __shared__ __align__(16) __hip_bfloat16 Bs[SBN][32];
    const int tid = threadIdx.x;
    const int lane = tid & 63, wid = tid >> 6;
    const int wm = wid >> 1, wn = wid & 1;
    const int row0 = blockIdx.x * SBM;
    const int h0 = blockIdx.y * SBN;
    const int lr = lane & 15, lg = lane >> 4;

    f32x4 acc[4][4] = {};

    for (int k0 = 0; k0 < HDIM; k0 += 32){
        #pragma unroll
        for (int l = 0; l < 2; l++){
            int f = tid + l * 256;
            int r = f >> 2, c8 = (f & 3) * 8;
            load_lds16(X + (size_t)(row0 + r) * HDIM + k0 + c8, &As[0][0] + f * 8);
            load_lds16(Kw + (size_t)(h0 + r) * HDIM + k0 + c8, &Bs[0][0] + f * 8);
        }
        __syncthreads();
        bf16x8 a[4], b[4];
        #pragma unroll
        for (int i = 0; i < 4; i++)
            a[i] = *(const bf16x8*)&As[wm * 64 + i * 16 + lr][lg * 8];
        #pragma unroll
        for (int j = 0; j < 4; j++)
            b[j] = *(const bf16x8*)&Bs[wn * 64 + j * 16 + lr][lg * 8];
        #pragma unroll
        for (int i = 0; i < 4; i++)
            #pragma unroll
            for (int j = 0; j < 4; j++)
                acc[i][j] = __builtin_amdgcn_mfma_f32_16x16x32_bf16(a[i], b[j], acc[i][j], 0, 0, 0);
        __syncthreads();
    }

    float kbv[4], vwv[4];
    #pragma unroll
    for (int j = 0; j < 4; j++){
        int h = h0 + wn * 64 + j * 16 + lr;
        kbv[j] = Kb[h]; vwv[j] = vw[h];
    }
    #pragma unroll
    for (int i = 0; i < 4; i++){
        #pragma unroll
        for (int reg = 0; reg < 4; reg++){
            int r = row0 + wm * 64 + i * 16 + lg * 4 + reg;
            int gr = row_off + r;
            int bb = gr / rows_per_batch;
            const float* Qpb = Qp + (size_t)bb * HDIM;
            float p = 0.f;
            #pragma unroll
            for (int j = 0; j < 4; j++){
                int h = h0 + wn * 64 + j * 16 + lr;
                p += tanh_fast(acc[i][j][reg] + kbv[j] + Qpb[h]) * vwv[j];
            }
            #pragma unroll
            for (int off = 1; off < 16; off <<= 1) p += __shfl_xor(p, off, 16);
            if (lr == 0) atomicAdd(&s[gr], p);
        }
    }
}

// in-place softmax over groups of Rg, grid = G blocks of 256
__global__ void softmax_kernel(float* __restrict__ s, int Rg){
    __shared__ float red[4];
    int g = blockIdx.x, tid = threadIdx.x;
    float* sg = s + (size_t)g * Rg;
    float m = -INFINITY;
    for (int i = tid; i < Rg; i += 256) m = fmaxf(m, sg[i]);
    #pragma unroll
    for (int off = 32; off > 0; off >>= 1) m = fmaxf(m, __shfl_down(m, off, 64));
    if ((tid & 63) == 0) red[tid >> 6] = m;
    __syncthreads();
    m = fmaxf(fmaxf(red[0], red[1]), fmaxf(red[2], red[3]));
    __syncthreads();
    float sum = 0.f;
    for (int i = tid; i < Rg; i += 256){ float e = __expf(sg[i] - m); sg[i] = e; sum += e; }
    #pragma unroll
    for (int off = 32; off > 0; off >>= 1) sum += __shfl_down(sum, off, 64);
    if ((tid & 63) == 0) red[tid >> 6] = sum;
    __syncthreads();
    float inv = 1.0f / (red[0] + red[1] + red[2] + red[3]);
    for (int i = tid; i < Rg; i += 256) sg[i] *= inv;
}

// f32 weighted sum
__global__ void wsum_kernel(const float* __restrict__ X, const float* __restrict__ sc,
                            float* __restrict__ out, int Rg, int rowsPerChunk){
    __shared__ float scs[256];
    int g = blockIdx.x >> 2;
    int kc = blockIdx.x & 3;
    int i0 = blockIdx.y * rowsPerChunk;
    int tid = threadIdx.x;
    if (tid < rowsPerChunk) scs[tid] = sc[(size_t)g * Rg + i0 + tid];
    __syncthreads();
    int k = kc * 256 + tid;
    const float* Xg = X + ((size_t)g * Rg + i0) * HDIM + k;
    float acc = 0.f;
    for (int i = 0; i < rowsPerChunk; i++)
        acc += scs[i] * Xg[(size_t)i * HDIM];
    atomicAdd(&out[(size_t)g * HDIM + k], acc);
}

// logits[b,j] = fb[j] + dot(feats[b,:5120], fw[j,:5120])  grid 32, block 256
__global__ void final_kernel(const float* __restrict__ feats, const float* __restrict__ fw,
                             const float* __restrict__ fb, float* __restrict__ out){
    __shared__ float red[4];
    int b = blockIdx.x, tid = threadIdx.x;
    const float* fe = feats + (size_t)b * 5120;
    for (int j = 0; j < 5; j++){
        float acc = 0.f;
        for (int i = tid; i < 5120; i += 256) acc += fe[i] * fw[(size_t)j * 5120 + i];
        #pragma unroll
        for (int off = 32; off > 0; off >>= 1) acc += __shfl_down(acc, off, 64);
        if ((tid & 63) == 0) red[tid >> 6] = acc;
        __syncthreads();
        if (tid == 0) out[b * 5 + j] = fb[j] + red[0] + red[1] + red[2] + red[3];
        __syncthreads();
    }
}

extern "C" void kernel_launch(void* const* d_in, const int* in_sizes, int n_in,
                              void* d_out, int out_size, void* d_ws, size_t ws_size,
                              hipStream_t stream) {
    const float* article  = (const float*)d_in[0];
    const float* question = (const float*)d_in[1];
    const float* options  = (const float*)d_in[2];
    const int*   ans      = (const int*)d_in[3];
    const float* a_Qw = (const float*)d_in[4];  const float* a_Qb = (const float*)d_in[5];
    const float* a_Kw = (const float*)d_in[6];  const float* a_Kb = (const float*)d_in[7];
    const float* a_Vw = (const float*)d_in[8];  const float* a_Vb = (const float*)d_in[9];
    const float* a_vw = (const float*)d_in[10];
    const float* d_Qw = (const float*)d_in[12]; const float* d_Qb = (const float*)d_in[13];
    const float* d_Kw = (const float*)d_in[14]; const float* d_Kb = (const float*)d_in[15];
    const float* d_Vw = (const float*)d_in[16]; const float* d_Vb = (const float*)d_in[17];
    const float* d_vw = (const float*)d_in[18];
    const float* f_w  = (const float*)d_in[20]; const float* f_b  = (const float*)d_in[21];
    float* out = (float*)d_out;

    float* ws = (float*)d_ws;
    float* oqc   = ws;               // 32768
    float* qp_a  = ws + 32768;       // 32768
    float* aq    = ws + 65536;       // 32768
    float* qp_d  = ws + 98304;       // 32768
    float* feats = ws + 131072;      // 163840
    float* s_art = ws + 294912;      // 65536  (zeroed)
    float* s_opt = ws + 360448;      // 5120   (zeroed)
    float* w_art = ws + 365568;      // 32768  (zeroed)
    float* wd    = ws + 398336;      // 163840 (zeroed)
    // bf16 region (weights + options only; article no longer converted)
    __hip_bfloat16* kwa_bf = (__hip_bfloat16*)(ws + 562176);
    __hip_bfloat16* kwd_bf = kwa_bf + 1048576;
    __hip_bfloat16* opt_bf = kwd_bf + 1048576;       // 5242880 elems

    zero_kernel<<<256, 256, 0, stream>>>(s_art, 267264);
    gather_kernel<<<NB, 256, 0, stream>>>(question, ans, oqc);
    proj_kernel<<<dim3(NB, 16), 256, 0, stream>>>(oqc, a_Qw, a_Qb, qp_a);
    conv_bf16_kernel<<<64, 256, 0, stream>>>(a_Kw, kwa_bf, 1048576);

    // single article score dispatch: na = 65536/256 = 256 (div by 8), grid 2048
    score_mfma_f32b<<<(NB * LA / 256) * 8, 512, 0, stream>>>(
        article, kwa_bf, a_Kb, qp_a, a_vw, s_art, LA);
    softmax_kernel<<<NB, 256, 0, stream>>>(s_art, LA);
    wsum_kernel<<<dim3(NB * 4, 8), 256, 0, stream>>>(article, s_art, w_art, LA, 256);
    proj_kernel<<<dim3(NB, 16), 256, 0, stream>>>(w_art, a_Vw, a_Vb, aq);

    proj_kernel<<<dim3(NB, 16), 256, 0, stream>>>(aq, d_Qw, d_Qb, qp_d);
    conv_bf16_kernel<<<64, 256, 0, stream>>>(d_Kw, kwd_bf, 1048576);
    conv_bf16_kernel<<<320, 256, 0, stream>>>(options, opt_bf, 5242880);
    score_mfma_kernel<<<dim3((NB * 5 * LO) / SBM, HDIM / SBN), 256, 0, stream>>>(
        opt_bf, kwd_bf, d_Kb, qp_d, d_vw, s_opt, 0, 5 * LO);
    softmax_kernel<<<NB * 5, 256, 0, stream>>>(s_opt, LO);
    wsum_kernel<<<dim3(NB * 5 * 4, 1), 256, 0, stream>>>(options, s_opt, wd, LO, LO);
    proj_kernel<<<dim3(NB * 5, 16), 256, 0, stream>>>(wd, d_Vw, d_Vb, feats);
    final_kernel<<<NB, 256, 0, stream>>>(feats, f_w, f_b, out);
}

// Round 12
// 471.055 us; speedup vs baseline: 1.0403x; 1.0403x over previous
//
#include <hip/hip_runtime.h>
#include <hip/hip_bf16.h>
#include <math.h>

#define HDIM 1024
#define NB 32
#define LA 2048
#define LO 32

typedef __attribute__((ext_vector_type(8))) short bf16x8;
typedef __attribute__((ext_vector_type(4))) float f32x4;
typedef unsigned int u32;

__device__ __forceinline__ float tanh_fast(float x){
    return 2.0f / (1.0f + __expf(-2.0f * x)) - 1.0f;
}

__device__ __forceinline__ void load_lds16(const void* gptr, void* lptr){
    __builtin_amdgcn_global_load_lds(
        (const __attribute__((address_space(1))) u32*)gptr,
        (__attribute__((address_space(3))) u32*)lptr, 16, 0, 0);
}

__global__ void zero_kernel(float* __restrict__ p, int n){
    int i = blockIdx.x * blockDim.x + threadIdx.x;
    int stride = gridDim.x * blockDim.x;
    for (; i < n; i += stride) p[i] = 0.0f;
}

__global__ void conv_bf16_kernel(const float* __restrict__ in, __hip_bfloat16* __restrict__ out, long n){
    long i = ((long)blockIdx.x * blockDim.x + threadIdx.x) * 4;
    long stride = (long)gridDim.x * blockDim.x * 4;
    for (; i < n; i += stride){
        float4 v = *(const float4*)(in + i);
        union { __hip_bfloat16 h[4]; short4 s; } u;
        u.h[0] = __float2bfloat16(v.x); u.h[1] = __float2bfloat16(v.y);
        u.h[2] = __float2bfloat16(v.z); u.h[3] = __float2bfloat16(v.w);
        *(short4*)(out + i) = u.s;
    }
}

__global__ void gather_kernel(const float* __restrict__ qc, const int* __restrict__ ans,
                              float* __restrict__ oqc){
    int b = blockIdx.x, tid = threadIdx.x;
    int idx = ans[b];
    const float* src = qc + ((size_t)b * 64 + idx) * HDIM;
    float* dst = oqc + (size_t)b * HDIM;
    #pragma unroll
    for (int l = 0; l < 4; l++) dst[tid + l * 256] = src[tid + l * 256];
}

// out[g,h] = bias[h] + dot(in[g,:], W[h,:])   grid (G, 16), block 256 (4 waves).
__global__ __launch_bounds__(256) void proj_kernel(
    const float* __restrict__ in, const float* __restrict__ W,
    const float* __restrict__ bias, float* __restrict__ out){
    __shared__ float xin[HDIM];
    const int g = blockIdx.x, tid = threadIdx.x;
    const int lane = tid & 63, wave = tid >> 6;
    *(float4*)&xin[tid * 4] = *(const float4*)&in[(size_t)g * HDIM + tid * 4];
    __syncthreads();
    float4 xv[4];
    #pragma unroll
    for (int c = 0; c < 4; c++) xv[c] = *(const float4*)&xin[(c * 64 + lane) * 4];
    const int hbase = blockIdx.y * 64 + wave * 16;
    #pragma unroll 4
    for (int r = 0; r < 16; r++){
        int h = hbase + r;
        const float* Wr = W + (size_t)h * HDIM;
        float p = 0.f;
        #pragma unroll
        for (int c = 0; c < 4; c++){
            float4 wv = *(const float4*)&Wr[(c * 64 + lane) * 4];
            p = fmaf(xv[c].x, wv.x, p); p = fmaf(xv[c].y, wv.y, p);
            p = fmaf(xv[c].z, wv.z, p); p = fmaf(xv[c].w, wv.w, p);
        }
        #pragma unroll
        for (int off = 1; off < 64; off <<= 1) p += __shfl_xor(p, off, 64);
        if (lane == 0) out[(size_t)g * HDIM + h] = p + bias[h];
    }
}

// ---------------- 128h x 128a article score kernel, f32-B DMA -----------------
// C[h, article] = Kw-bf16 (A, global_load_lds) x article-f32 (B, global_load_lds
// of raw f32, converted to bf16 at fragment-read). 8 waves of 64h x 32a. BK=32.
// LDS per buf: A 8KB (bf16, 64B rows, R8 swizzle) + B 16KB (f32, 128B rows,
// slot sigma stored at sigma^(rho&7) -> b128 reads hit the 8-slot spread floor).
// 2 bufs = 48KB -> 2 blocks/CU. R8's proven counted-vmcnt(3) 2-barrier pipeline.
// Eliminates the article bf16 pre-pass. XCD decode needs na % 8 == 0 (na=512).
#define NT 32   // K tiles = 1024/32
__global__ __launch_bounds__(512, 4) void score_f32b(
    const float* __restrict__ Xf, const __hip_bfloat16* __restrict__ Kw,
    const float* __restrict__ Kb, const float* __restrict__ Qp,
    const float* __restrict__ vw, float* __restrict__ s,
    int rows_per_batch)
{
    __shared__ __align__(16) char lds[49152];
    const int tid = threadIdx.x;
    const int lane = tid & 63, wid = tid >> 6;
    const int wm = wid >> 2, wn = wid & 3;
    const int lr = lane & 15, lg = lane >> 4;

    const int na = gridDim.x >> 3;          // article tiles of 128 rows (512)
    const int bid = blockIdx.x;
    const int xcd = bid & 7, seq = bid >> 3;
    const int a_idx = xcd * (na >> 3) + (seq >> 3);
    const int h_idx = seq & 7;              // 8 h-tiles of 128
    const int a0 = a_idx * 128, h0 = h_idx * 128;

    f32x4 acc[4][2] = {};

    // ---- A staging: bf16 Kw, 64B rows, inverse-swizzled source (R8) ----
    const int rA = tid >> 2;                              // 0..127
    const int srcbA = ((tid & 3) * 16) ^ (((rA >> 1) & 3) << 4);
    const char* pA = (const char*)Kw + (size_t)(h0 + rA) * 2048 + srcbA;
    char* dA = lds + tid * 16;

    // ---- B staging: f32 article, 128B rows; chunk sigma stored at slot
    // sigma^(rho&7). Two issues cover rows 0-63 / 64-127; (rho+64)&7 == rho&7.
    const int rho0 = tid >> 3, s0 = tid & 7;
    const int sigB = (s0 ^ (rho0 & 7)) * 16;
    const char* pB0 = (const char*)Xf + (size_t)(a0 + rho0) * 4096 + sigB;
    const char* pB1 = (const char*)Xf + (size_t)(a0 + rho0 + 64) * 4096 + sigB;
    char* dB0 = lds + 8192 + tid * 16;
    char* dB1 = lds + 16384 + tid * 16;

    // ---- LDS read offsets ----
    int aoff[4];
    #pragma unroll
    for (int hf = 0; hf < 4; hf++){
        int rw = wm * 64 + hf * 16 + lr;
        aoff[hf] = rw * 64 + ((lg * 16) ^ (((rw >> 1) & 3) << 4));
    }
    int boff[2][2];
    #pragma unroll
    for (int af = 0; af < 2; af++){
        int rho = wn * 32 + af * 16 + lr;
        boff[af][0] = 8192 + rho * 128 + (((2 * lg)     ^ (rho & 7)) * 16);
        boff[af][1] = 8192 + rho * 128 + (((2 * lg + 1) ^ (rho & 7)) * 16);
    }

#define STAGE(kt, bufoff) do { \
    load_lds16(pA  + (size_t)(kt) * 64,  dA  + (bufoff)); \
    load_lds16(pB0 + (size_t)(kt) * 128, dB0 + (bufoff)); \
    load_lds16(pB1 + (size_t)(kt) * 128, dB1 + (bufoff)); } while(0)

#define COMPUTE(bufoff) do { \
    bf16x8 av[4], bv[2]; \
    _Pragma("unroll") \
    for (int hf = 0; hf < 4; hf++) av[hf] = *(const bf16x8*)(lds + (bufoff) + aoff[hf]); \
    _Pragma("unroll") \
    for (int af = 0; af < 2; af++){ \
        f32x4 x0 = *(const f32x4*)(lds + (bufoff) + boff[af][0]); \
        f32x4 x1 = *(const f32x4*)(lds + (bufoff) + boff[af][1]); \
        union { __hip_bfloat16 h[8]; bf16x8 v; } u; \
        u.h[0] = __float2bfloat16(x0[0]); u.h[1] = __float2bfloat16(x0[1]); \
        u.h[2] = __float2bfloat16(x0[2]); u.h[3] = __float2bfloat16(x0[3]); \
        u.h[4] = __float2bfloat16(x1[0]); u.h[5] = __float2bfloat16(x1[1]); \
        u.h[6] = __float2bfloat16(x1[2]); u.h[7] = __float2bfloat16(x1[3]); \
        bv[af] = u.v; \
    } \
    __builtin_amdgcn_s_setprio(1); \
    _Pragma("unroll") \
    for (int hf = 0; hf < 4; hf++) \
        _Pragma("unroll") \
        for (int af = 0; af < 2; af++) \
            acc[hf][af] = __builtin_amdgcn_mfma_f32_16x16x32_bf16(av[hf], bv[af], acc[hf][af], 0, 0, 0); \
    __builtin_amdgcn_s_setprio(0); } while(0)

    STAGE(0, 0);
    STAGE(1, 24576);
    int bo = 0;
    for (int kt = 0; kt < NT - 1; ++kt){
        asm volatile("s_waitcnt vmcnt(3)" ::: "memory");
        __builtin_amdgcn_s_barrier();
        __builtin_amdgcn_sched_barrier(0);
        COMPUTE(bo);
        __builtin_amdgcn_s_barrier();
        if (kt < NT - 2) STAGE(kt + 2, bo);
        bo ^= 24576;
    }
    asm volatile("s_waitcnt vmcnt(0)" ::: "memory");
    __builtin_amdgcn_s_barrier();
    __builtin_amdgcn_sched_barrier(0);
    COMPUTE(bo);

    // epilogue: C rows (h) = lg*4+r within frag hf; C col (article) = lr
    const int b = a0 / rows_per_batch;  // uniform: 128 | 2048
    float qv[4][4], vv[4][4];
    #pragma unroll
    for (int hf = 0; hf < 4; hf++){
        int hbase = h0 + wm * 64 + hf * 16 + lg * 4;
        float4 kb4 = *(const float4*)(Kb + hbase);
        float4 qp4 = *(const float4*)(Qp + (size_t)b * HDIM + hbase);
        float4 vw4 = *(const float4*)(vw + hbase);
        qv[hf][0] = kb4.x + qp4.x; qv[hf][1] = kb4.y + qp4.y;
        qv[hf][2] = kb4.z + qp4.z; qv[hf][3] = kb4.w + qp4.w;
        vv[hf][0] = vw4.x; vv[hf][1] = vw4.y; vv[hf][2] = vw4.z; vv[hf][3] = vw4.w;
    }
    #pragma unroll
    for (int af = 0; af < 2; af++){
        float sacc = 0.f;
        #pragma unroll
        for (int hf = 0; hf < 4; hf++)
            #pragma unroll
            for (int r = 0; r < 4; r++)
                sacc += tanh_fast(acc[hf][af][r] + qv[hf][r]) * vv[hf][r];
        sacc += __shfl_xor(sacc, 16, 64);
        sacc += __shfl_xor(sacc, 32, 64);
        if (lane < 16)
            atomicAdd(&s[a0 + wn * 32 + af * 16 + lr], sacc);
    }
#undef STAGE
#undef COMPUTE
}

// ---------------- old 128x128 4-wave score kernel (option path) --------------
#define SBM 128
#define SBN 128
__global__ __launch_bounds__(256) void score_mfma_kernel(
    const __hip_bfloat16* __restrict__ X, const __hip_bfloat16* __restrict__ Kw,
    const float* __restrict__ Kb, const float* __restrict__ Qp,
    const float* __restrict__ vw, float* __restrict__ s,
    int row_off, int rows_per_batch)
{
    __shared__ __align__(16) __hip_bfloat16 As[SBM][32];
    __shared__ __align__(16) __hip_bfloat16 Bs[SBN][32];
    const int tid = threadIdx.x;
    const int lane = tid & 63, wid = tid >> 6;
    const int wm = wid >> 1, wn = wid & 1;
    const int row0 = blockIdx.x * SBM;
    const int h0 = blockIdx.y * SBN;
    const int lr = lane & 15, lg = lane >> 4;

    f32x4 acc[4][4] = {};

    for (int k0 = 0; k0 < HDIM; k0 += 32){
        #pragma unroll
        for (int l = 0; l < 2; l++){
            int f = tid + l * 256;
            int r = f >> 2, c8 = (f & 3) * 8;
            load_lds16(X + (size_t)(row0 + r) * HDIM + k0 + c8, &As[0][0] + f * 8);
            load_lds16(Kw + (size_t)(h0 + r) * HDIM + k0 + c8, &Bs[0][0] + f * 8);
        }
        __syncthreads();
        bf16x8 a[4], b[4];
        #pragma unroll
        for (int i = 0; i < 4; i++)
            a[i] = *(const bf16x8*)&As[wm * 64 + i * 16 + lr][lg * 8];
        #pragma unroll
        for (int j = 0; j < 4; j++)
            b[j] = *(const bf16x8*)&Bs[wn * 64 + j * 16 + lr][lg * 8];
        #pragma unroll
        for (int i = 0; i < 4; i++)
            #pragma unroll
            for (int j = 0; j < 4; j++)
                acc[i][j] = __builtin_amdgcn_mfma_f32_16x16x32_bf16(a[i], b[j], acc[i][j], 0, 0, 0);
        __syncthreads();
    }

    float kbv[4], vwv[4];
    #pragma unroll
    for (int j = 0; j < 4; j++){
        int h = h0 + wn * 64 + j * 16 + lr;
        kbv[j] = Kb[h]; vwv[j] = vw[h];
    }
    #pragma unroll
    for (int i = 0; i < 4; i++){
        #pragma unroll
        for (int reg = 0; reg < 4; reg++){
            int r = row0 + wm * 64 + i * 16 + lg * 4 + reg;
            int gr = row_off + r;
            int bb = gr / rows_per_batch;
            const float* Qpb = Qp + (size_t)bb * HDIM;
            float p = 0.f;
            #pragma unroll
            for (int j = 0; j < 4; j++){
                int h = h0 + wn * 64 + j * 16 + lr;
                p += tanh_fast(acc[i][j][reg] + kbv[j] + Qpb[h]) * vwv[j];
            }
            #pragma unroll
            for (int off = 1; off < 16; off <<= 1) p += __shfl_xor(p, off, 16);
            if (lr == 0) atomicAdd(&s[gr], p);
        }
    }
}

// in-place softmax over groups of Rg, grid = G blocks of 256
__global__ void softmax_kernel(float* __restrict__ s, int Rg){
    __shared__ float red[4];
    int g = blockIdx.x, tid = threadIdx.x;
    float* sg = s + (size_t)g * Rg;
    float m = -INFINITY;
    for (int i = tid; i < Rg; i += 256) m = fmaxf(m, sg[i]);
    #pragma unroll
    for (int off = 32; off > 0; off >>= 1) m = fmaxf(m, __shfl_down(m, off, 64));
    if ((tid & 63) == 0) red[tid >> 6] = m;
    __syncthreads();
    m = fmaxf(fmaxf(red[0], red[1]), fmaxf(red[2], red[3]));
    __syncthreads();
    float sum = 0.f;
    for (int i = tid; i < Rg; i += 256){ float e = __expf(sg[i] - m); sg[i] = e; sum += e; }
    #pragma unroll
    for (int off = 32; off > 0; off >>= 1) sum += __shfl_down(sum, off, 64);
    if ((tid & 63) == 0) red[tid >> 6] = sum;
    __syncthreads();
    float inv = 1.0f / (red[0] + red[1] + red[2] + red[3]);
    for (int i = tid; i < Rg; i += 256) sg[i] *= inv;
}

// f32 weighted sum
__global__ void wsum_kernel(const float* __restrict__ X, const float* __restrict__ sc,
                            float* __restrict__ out, int Rg, int rowsPerChunk){
    __shared__ float scs[256];
    int g = blockIdx.x >> 2;
    int kc = blockIdx.x & 3;
    int i0 = blockIdx.y * rowsPerChunk;
    int tid = threadIdx.x;
    if (tid < rowsPerChunk) scs[tid] = sc[(size_t)g * Rg + i0 + tid];
    __syncthreads();
    int k = kc * 256 + tid;
    const float* Xg = X + ((size_t)g * Rg + i0) * HDIM + k;
    float acc = 0.f;
    for (int i = 0; i < rowsPerChunk; i++)
        acc += scs[i] * Xg[(size_t)i * HDIM];
    atomicAdd(&out[(size_t)g * HDIM + k], acc);
}

// logits[b,j] = fb[j] + dot(feats[b,:5120], fw[j,:5120])  grid 32, block 256
__global__ void final_kernel(const float* __restrict__ feats, const float* __restrict__ fw,
                             const float* __restrict__ fb, float* __restrict__ out){
    __shared__ float red[4];
    int b = blockIdx.x, tid = threadIdx.x;
    const float* fe = feats + (size_t)b * 5120;
    for (int j = 0; j < 5; j++){
        float acc = 0.f;
        for (int i = tid; i < 5120; i += 256) acc += fe[i] * fw[(size_t)j * 5120 + i];
        #pragma unroll
        for (int off = 32; off > 0; off >>= 1) acc += __shfl_down(acc, off, 64);
        if ((tid & 63) == 0) red[tid >> 6] = acc;
        __syncthreads();
        if (tid == 0) out[b * 5 + j] = fb[j] + red[0] + red[1] + red[2] + red[3];
        __syncthreads();
    }
}

extern "C" void kernel_launch(void* const* d_in, const int* in_sizes, int n_in,
                              void* d_out, int out_size, void* d_ws, size_t ws_size,
                              hipStream_t stream) {
    const float* article  = (const float*)d_in[0];
    const float* question = (const float*)d_in[1];
    const float* options  = (const float*)d_in[2];
    const int*   ans      = (const int*)d_in[3];
    const float* a_Qw = (const float*)d_in[4];  const float* a_Qb = (const float*)d_in[5];
    const float* a_Kw = (const float*)d_in[6];  const float* a_Kb = (const float*)d_in[7];
    const float* a_Vw = (const float*)d_in[8];  const float* a_Vb = (const float*)d_in[9];
    const float* a_vw = (const float*)d_in[10];
    const float* d_Qw = (const float*)d_in[12]; const float* d_Qb = (const float*)d_in[13];
    const float* d_Kw = (const float*)d_in[14]; const float* d_Kb = (const float*)d_in[15];
    const float* d_Vw = (const float*)d_in[16]; const float* d_Vb = (const float*)d_in[17];
    const float* d_vw = (const float*)d_in[18];
    const float* f_w  = (const float*)d_in[20]; const float* f_b  = (const float*)d_in[21];
    float* out = (float*)d_out;

    float* ws = (float*)d_ws;
    float* oqc   = ws;               // 32768
    float* qp_a  = ws + 32768;       // 32768
    float* aq    = ws + 65536;       // 32768
    float* qp_d  = ws + 98304;       // 32768
    float* feats = ws + 131072;      // 163840
    float* s_art = ws + 294912;      // 65536  (zeroed)
    float* s_opt = ws + 360448;      // 5120   (zeroed)
    float* w_art = ws + 365568;      // 32768  (zeroed)
    float* wd    = ws + 398336;      // 163840 (zeroed)
    // bf16 region (weights + options only; article never converted)
    __hip_bfloat16* kwa_bf = (__hip_bfloat16*)(ws + 562176);
    __hip_bfloat16* kwd_bf = kwa_bf + 1048576;
    __hip_bfloat16* opt_bf = kwd_bf + 1048576;       // 5242880 elems

    zero_kernel<<<256, 256, 0, stream>>>(s_art, 267264);
    gather_kernel<<<NB, 256, 0, stream>>>(question, ans, oqc);
    proj_kernel<<<dim3(NB, 16), 256, 0, stream>>>(oqc, a_Qw, a_Qb, qp_a);
    conv_bf16_kernel<<<64, 256, 0, stream>>>(a_Kw, kwa_bf, 1048576);

    // single article score dispatch: na = 65536/128 = 512 (div by 8), grid 4096
    score_f32b<<<(NB * LA / 128) * 8, 512, 0, stream>>>(
        article, kwa_bf, a_Kb, qp_a, a_vw, s_art, LA);
    softmax_kernel<<<NB, 256, 0, stream>>>(s_art, LA);
    wsum_kernel<<<dim3(NB * 4, 8), 256, 0, stream>>>(article, s_art, w_art, LA, 256);
    proj_kernel<<<dim3(NB, 16), 256, 0, stream>>>(w_art, a_Vw, a_Vb, aq);

    proj_kernel<<<dim3(NB, 16), 256, 0, stream>>>(aq, d_Qw, d_Qb, qp_d);
    conv_bf16_kernel<<<64, 256, 0, stream>>>(d_Kw, kwd_bf, 1048576);
    conv_bf16_kernel<<<320, 256, 0, stream>>>(options, opt_bf, 5242880);
    score_mfma_kernel<<<dim3((NB * 5 * LO) / SBM, HDIM / SBN), 256, 0, stream>>>(
        opt_bf, kwd_bf, d_Kb, qp_d, d_vw, s_opt, 0, 5 * LO);
    softmax_kernel<<<NB * 5, 256, 0, stream>>>(s_opt, LO);
    wsum_kernel<<<dim3(NB * 5 * 4, 1), 256, 0, stream>>>(options, s_opt, wd, LO, LO);
    proj_kernel<<<dim3(NB * 5, 16), 256, 0, stream>>>(wd, d_Vw, d_Vb, feats);
    final_kernel<<<NB, 256, 0, stream>>>(feats, f_w, f_b, out);
}

// Round 13
// 425.481 us; speedup vs baseline: 1.1517x; 1.1071x over previous
//
#include <hip/hip_runtime.h>
#include <hip/hip_bf16.h>
#include <math.h>

#define HDIM 1024
#define NB 32
#define LA 2048
#define LO 32

typedef __attribute__((ext_vector_type(8))) short bf16x8;
typedef __attribute__((ext_vector_type(4))) float f32x4;
typedef unsigned int u32;

__device__ __forceinline__ float tanh_fast(float x){
    return 2.0f / (1.0f + __expf(-2.0f * x)) - 1.0f;
}

__device__ __forceinline__ void load_lds16(const void* gptr, void* lptr){
    __builtin_amdgcn_global_load_lds(
        (const __attribute__((address_space(1))) u32*)gptr,
        (__attribute__((address_space(3))) u32*)lptr, 16, 0, 0);
}

__global__ void zero_kernel(float* __restrict__ p, int n){
    int i = blockIdx.x * blockDim.x + threadIdx.x;
    int stride = gridDim.x * blockDim.x;
    for (; i < n; i += stride) p[i] = 0.0f;
}

__global__ void conv_bf16_kernel(const float* __restrict__ in, __hip_bfloat16* __restrict__ out, long n){
    long i = ((long)blockIdx.x * blockDim.x + threadIdx.x) * 4;
    long stride = (long)gridDim.x * blockDim.x * 4;
    for (; i < n; i += stride){
        float4 v = *(const float4*)(in + i);
        union { __hip_bfloat16 h[4]; short4 s; } u;
        u.h[0] = __float2bfloat16(v.x); u.h[1] = __float2bfloat16(v.y);
        u.h[2] = __float2bfloat16(v.z); u.h[3] = __float2bfloat16(v.w);
        *(short4*)(out + i) = u.s;
    }
}

// dual-range conversion: blocks [0,64) -> (in0,n0); [64,384) -> (in1,n1)
__global__ void conv2_bf16_kernel(const float* __restrict__ in0, __hip_bfloat16* __restrict__ out0, long n0,
                                  const float* __restrict__ in1, __hip_bfloat16* __restrict__ out1, long n1){
    const float* in; __hip_bfloat16* out; long n; long base;
    if (blockIdx.x < 64){ in = in0; out = out0; n = n0; base = (long)blockIdx.x; 
        long i = (base * blockDim.x + threadIdx.x) * 4;
        long stride = 64L * blockDim.x * 4;
        for (; i < n; i += stride){
            float4 v = *(const float4*)(in + i);
            union { __hip_bfloat16 h[4]; short4 s; } u;
            u.h[0] = __float2bfloat16(v.x); u.h[1] = __float2bfloat16(v.y);
            u.h[2] = __float2bfloat16(v.z); u.h[3] = __float2bfloat16(v.w);
            *(short4*)(out + i) = u.s;
        }
    } else { in = in1; out = out1; n = n1; base = (long)(blockIdx.x - 64);
        long i = (base * blockDim.x + threadIdx.x) * 4;
        long stride = 320L * blockDim.x * 4;
        for (; i < n; i += stride){
            float4 v = *(const float4*)(in + i);
            union { __hip_bfloat16 h[4]; short4 s; } u;
            u.h[0] = __float2bfloat16(v.x); u.h[1] = __float2bfloat16(v.y);
            u.h[2] = __float2bfloat16(v.z); u.h[3] = __float2bfloat16(v.w);
            *(short4*)(out + i) = u.s;
        }
    }
}

// fused gather+proj: out[g,h] = bias[h] + dot(question[g, ans[g]], W[h,:])
__global__ __launch_bounds__(256) void proj_q_kernel(
    const float* __restrict__ question, const int* __restrict__ ans,
    const float* __restrict__ W, const float* __restrict__ bias, float* __restrict__ out){
    __shared__ float xin[HDIM];
    const int g = blockIdx.x, tid = threadIdx.x;
    const int lane = tid & 63, wave = tid >> 6;
    const float* in = question + ((size_t)g * 64 + ans[g]) * HDIM;
    *(float4*)&xin[tid * 4] = *(const float4*)&in[tid * 4];
    __syncthreads();
    float4 xv[4];
    #pragma unroll
    for (int c = 0; c < 4; c++) xv[c] = *(const float4*)&xin[(c * 64 + lane) * 4];
    const int hbase = blockIdx.y * 64 + wave * 16;
    #pragma unroll 4
    for (int r = 0; r < 16; r++){
        int h = hbase + r;
        const float* Wr = W + (size_t)h * HDIM;
        float p = 0.f;
        #pragma unroll
        for (int c = 0; c < 4; c++){
            float4 wv = *(const float4*)&Wr[(c * 64 + lane) * 4];
            p = fmaf(xv[c].x, wv.x, p); p = fmaf(xv[c].y, wv.y, p);
            p = fmaf(xv[c].z, wv.z, p); p = fmaf(xv[c].w, wv.w, p);
        }
        #pragma unroll
        for (int off = 1; off < 64; off <<= 1) p += __shfl_xor(p, off, 64);
        if (lane == 0) out[(size_t)g * HDIM + h] = p + bias[h];
    }
}

// out[g,h] = bias[h] + dot(in[g,:], W[h,:])   grid (G, 16), block 256 (4 waves).
__global__ __launch_bounds__(256) void proj_kernel(
    const float* __restrict__ in, const float* __restrict__ W,
    const float* __restrict__ bias, float* __restrict__ out){
    __shared__ float xin[HDIM];
    const int g = blockIdx.x, tid = threadIdx.x;
    const int lane = tid & 63, wave = tid >> 6;
    *(float4*)&xin[tid * 4] = *(const float4*)&in[(size_t)g * HDIM + tid * 4];
    __syncthreads();
    float4 xv[4];
    #pragma unroll
    for (int c = 0; c < 4; c++) xv[c] = *(const float4*)&xin[(c * 64 + lane) * 4];
    const int hbase = blockIdx.y * 64 + wave * 16;
    #pragma unroll 4
    for (int r = 0; r < 16; r++){
        int h = hbase + r;
        const float* Wr = W + (size_t)h * HDIM;
        float p = 0.f;
        #pragma unroll
        for (int c = 0; c < 4; c++){
            float4 wv = *(const float4*)&Wr[(c * 64 + lane) * 4];
            p = fmaf(xv[c].x, wv.x, p); p = fmaf(xv[c].y, wv.y, p);
            p = fmaf(xv[c].z, wv.z, p); p = fmaf(xv[c].w, wv.w, p);
        }
        #pragma unroll
        for (int off = 1; off < 64; off <<= 1) p += __shfl_xor(p, off, 64);
        if (lane == 0) out[(size_t)g * HDIM + h] = p + bias[h];
    }
}

// ---------------- 256h x 256a phase-split article score kernel (R9) -----------
#define NTT 16
__global__ __launch_bounds__(512, 2) void score_mfma8p(
    const __hip_bfloat16* __restrict__ X, const __hip_bfloat16* __restrict__ Kw,
    const float* __restrict__ Kb, const float* __restrict__ Qp,
    const float* __restrict__ vw, float* __restrict__ s,
    int rows_per_batch)
{
    __shared__ __align__(16) char lds[131072];
    const int tid = threadIdx.x;
    const int lane = tid & 63, wid = tid >> 6;
    const int wm = wid >> 2, wn = wid & 3;
    const int lr = lane & 15, lg = lane >> 4;

    const int na = gridDim.x >> 2;
    const int bid = blockIdx.x;
    const int xcd = bid & 7, seq = bid >> 3;
    const int a_idx = xcd * (na >> 3) + (seq >> 2);
    const int h_idx = seq & 3;
    const int a0 = a_idx * 256, h0 = h_idx * 256;

    f32x4 acc[8][4] = {};
    bf16x8 av[8], bv[4];

    const int rA = tid >> 2;
    const int csw = ((tid & 3) * 16) ^ (((rA >> 1) & 3) << 4);
    const char* pA = (const char*)Kw + (size_t)(h0 + rA) * 2048 + csw;
    const char* pB = (const char*)X  + (size_t)(a0 + rA) * 2048 + csw;
    char* dst0 = lds + tid * 16;

    int aoff[8], boff[4];
    #pragma unroll
    for (int hf = 0; hf < 8; hf++){
        int rw = wm * 128 + hf * 16 + lr;
        aoff[hf] = rw * 64 + ((lg * 16) ^ (((rw >> 1) & 3) << 4));
    }
    #pragma unroll
    for (int af = 0; af < 4; af++){
        int rw = wn * 64 + af * 16 + lr;
        boff[af] = 16384 + rw * 64 + ((lg * 16) ^ (((rw >> 1) & 3) << 4));
    }

#define ISSUE(P, KOFF, SLOT, PLANE) do { \
    load_lds16((P) + (KOFF), dst0 + (SLOT) + (PLANE)); \
    load_lds16((P) + (KOFF) + 262144, dst0 + (SLOT) + (PLANE) + 8192); } while(0)
#define READS_A(BASE) do { \
    _Pragma("unroll") \
    for (int hf = 0; hf < 8; hf++) av[hf] = *(const bf16x8*)(lds + (BASE) + aoff[hf]); \
    bv[0] = *(const bf16x8*)(lds + (BASE) + boff[0]); \
    bv[1] = *(const bf16x8*)(lds + (BASE) + boff[1]); } while(0)
#define READS_B(BASE) do { \
    bv[2] = *(const bf16x8*)(lds + (BASE) + boff[2]); \
    bv[3] = *(const bf16x8*)(lds + (BASE) + boff[3]); } while(0)
#define MFMA2(A0, A1) do { __builtin_amdgcn_s_setprio(1); \
    _Pragma("unroll") \
    for (int hf = 0; hf < 8; hf++){ \
        acc[hf][A0] = __builtin_amdgcn_mfma_f32_16x16x32_bf16(av[hf], bv[A0], acc[hf][A0], 0, 0, 0); \
        acc[hf][A1] = __builtin_amdgcn_mfma_f32_16x16x32_bf16(av[hf], bv[A1], acc[hf][A1], 0, 0, 0); } \
    __builtin_amdgcn_s_setprio(0); } while(0)
#define BAR() __builtin_amdgcn_s_barrier()

    ISSUE(pA, 0, 0, 0);        ISSUE(pB, 0, 0, 16384);
    ISSUE(pA, 64, 0, 32768);   ISSUE(pB, 64, 0, 49152);
    ISSUE(pA, 128, 65536, 0);  ISSUE(pB, 128, 65536, 16384);

    for (int t = 0; t < 14; ++t){
        const int st = (t & 1) << 16;
        const int so = st ^ 65536;
        const int kb = t * 128;
        ISSUE(pA, kb + 192, so, 32768);
        asm volatile("s_waitcnt vmcnt(10)" ::: "memory");
        BAR();
        READS_A(st);
        BAR();
        MFMA2(0, 1);
        ISSUE(pB, kb + 192, so, 49152);
        READS_B(st);
        BAR();
        MFMA2(2, 3);
        ISSUE(pA, kb + 256, st, 0);
        asm volatile("s_waitcnt vmcnt(10)" ::: "memory");
        BAR();
        READS_A(st + 32768);
        BAR();
        MFMA2(0, 1);
        ISSUE(pB, kb + 256, st, 16384);
        READS_B(st + 32768);
        BAR();
        MFMA2(2, 3);
    }
    {
        ISSUE(pA, 14 * 128 + 192, 65536, 32768);
        asm volatile("s_waitcnt vmcnt(10)" ::: "memory");
        BAR(); READS_A(0); BAR(); MFMA2(0, 1);
        ISSUE(pB, 14 * 128 + 192, 65536, 49152);
        READS_B(0); BAR(); MFMA2(2, 3);
        asm volatile("s_waitcnt vmcnt(8)" ::: "memory");
        BAR(); READS_A(32768); BAR(); MFMA2(0, 1);
        READS_B(32768); BAR(); MFMA2(2, 3);
    }
    {
        asm volatile("s_waitcnt vmcnt(4)" ::: "memory");
        BAR(); READS_A(65536); BAR(); MFMA2(0, 1);
        READS_B(65536); BAR(); MFMA2(2, 3);
        asm volatile("s_waitcnt vmcnt(0)" ::: "memory");
        BAR(); READS_A(65536 + 32768); BAR(); MFMA2(0, 1);
        READS_B(65536 + 32768); BAR(); MFMA2(2, 3);
    }

    const int b = a0 / rows_per_batch;
    float part[4] = {0.f, 0.f, 0.f, 0.f};
    #pragma unroll
    for (int hf = 0; hf < 8; hf++){
        int hbase = h0 + wm * 128 + hf * 16 + lg * 4;
        float4 kb4 = *(const float4*)(Kb + hbase);
        float4 qp4 = *(const float4*)(Qp + (size_t)b * HDIM + hbase);
        float4 vw4 = *(const float4*)(vw + hbase);
        float q0v = kb4.x + qp4.x, q1v = kb4.y + qp4.y;
        float q2v = kb4.z + qp4.z, q3v = kb4.w + qp4.w;
        #pragma unroll
        for (int af = 0; af < 4; af++){
            part[af] += tanh_fast(acc[hf][af][0] + q0v) * vw4.x;
            part[af] += tanh_fast(acc[hf][af][1] + q1v) * vw4.y;
            part[af] += tanh_fast(acc[hf][af][2] + q2v) * vw4.z;
            part[af] += tanh_fast(acc[hf][af][3] + q3v) * vw4.w;
        }
    }
    #pragma unroll
    for (int af = 0; af < 4; af++){
        float p = part[af];
        p += __shfl_xor(p, 16, 64);
        p += __shfl_xor(p, 32, 64);
        if (lane < 16)
            atomicAdd(&s[a0 + wn * 64 + af * 16 + lr], p);
    }
#undef ISSUE
#undef READS_A
#undef READS_B
#undef MFMA2
#undef BAR
}

// ---------------- old 128x128 4-wave score kernel (option path) --------------
#define SBM 128
#define SBN 128
__global__ __launch_bounds__(256) void score_mfma_kernel(
    const __hip_bfloat16* __restrict__ X, const __hip_bfloat16* __restrict__ Kw,
    const float* __restrict__ Kb, const float* __restrict__ Qp,
    const float* __restrict__ vw, float* __restrict__ s,
    int row_off, int rows_per_batch)
{
    __shared__ __align__(16) __hip_bfloat16 As[SBM][32];
    __shared__ __align__(16) __hip_bfloat16 Bs[SBN][32];
    const int tid = threadIdx.x;
    const int lane = tid & 63, wid = tid >> 6;
    const int wm = wid >> 1, wn = wid & 1;
    const int row0 = blockIdx.x * SBM;
    const int h0 = blockIdx.y * SBN;
    const int lr = lane & 15, lg = lane >> 4;

    f32x4 acc[4][4] = {};

    for (int k0 = 0; k0 < HDIM; k0 += 32){
        #pragma unroll
        for (int l = 0; l < 2; l++){
            int f = tid + l * 256;
            int r = f >> 2, c8 = (f & 3) * 8;
            load_lds16(X + (size_t)(row0 + r) * HDIM + k0 + c8, &As[0][0] + f * 8);
            load_lds16(Kw + (size_t)(h0 + r) * HDIM + k0 + c8, &Bs[0][0] + f * 8);
        }
        __syncthreads();
        bf16x8 a[4], b[4];
        #pragma unroll
        for (int i = 0; i < 4; i++)
            a[i] = *(const bf16x8*)&As[wm * 64 + i * 16 + lr][lg * 8];
        #pragma unroll
        for (int j = 0; j < 4; j++)
            b[j] = *(const bf16x8*)&Bs[wn * 64 + j * 16 + lr][lg * 8];
        #pragma unroll
        for (int i = 0; i < 4; i++)
            #pragma unroll
            for (int j = 0; j < 4; j++)
                acc[i][j] = __builtin_amdgcn_mfma_f32_16x16x32_bf16(a[i], b[j], acc[i][j], 0, 0, 0);
        __syncthreads();
    }

    float kbv[4], vwv[4];
    #pragma unroll
    for (int j = 0; j < 4; j++){
        int h = h0 + wn * 64 + j * 16 + lr;
        kbv[j] = Kb[h]; vwv[j] = vw[h];
    }
    #pragma unroll
    for (int i = 0; i < 4; i++){
        #pragma unroll
        for (int reg = 0; reg < 4; reg++){
            int r = row0 + wm * 64 + i * 16 + lg * 4 + reg;
            int gr = row_off + r;
            int bb = gr / rows_per_batch;
            const float* Qpb = Qp + (size_t)bb * HDIM;
            float p = 0.f;
            #pragma unroll
            for (int j = 0; j < 4; j++){
                int h = h0 + wn * 64 + j * 16 + lr;
                p += tanh_fast(acc[i][j][reg] + kbv[j] + Qpb[h]) * vwv[j];
            }
            #pragma unroll
            for (int off = 1; off < 16; off <<= 1) p += __shfl_xor(p, off, 16);
            if (lr == 0) atomicAdd(&s[gr], p);
        }
    }
}

// in-place softmax over groups of Rg, grid = G blocks of 256
__global__ void softmax_kernel(float* __restrict__ s, int Rg){
    __shared__ float red[4];
    int g = blockIdx.x, tid = threadIdx.x;
    float* sg = s + (size_t)g * Rg;
    float m = -INFINITY;
    for (int i = tid; i < Rg; i += 256) m = fmaxf(m, sg[i]);
    #pragma unroll
    for (int off = 32; off > 0; off >>= 1) m = fmaxf(m, __shfl_down(m, off, 64));
    if ((tid & 63) == 0) red[tid >> 6] = m;
    __syncthreads();
    m = fmaxf(fmaxf(red[0], red[1]), fmaxf(red[2], red[3]));
    __syncthreads();
    float sum = 0.f;
    for (int i = tid; i < Rg; i += 256){ float e = __expf(sg[i] - m); sg[i] = e; sum += e; }
    #pragma unroll
    for (int off = 32; off > 0; off >>= 1) sum += __shfl_down(sum, off, 64);
    if ((tid & 63) == 0) red[tid >> 6] = sum;
    __syncthreads();
    float inv = 1.0f / (red[0] + red[1] + red[2] + red[3]);
    for (int i = tid; i < Rg; i += 256) sg[i] *= inv;
}

// vectorized bf16 weighted sum (article): grid (NB, 8), 256 thr, short4/thread
__global__ __launch_bounds__(256) void wsum_art_v(
    const __hip_bfloat16* __restrict__ X, const float* __restrict__ sc,
    float* __restrict__ out){
    __shared__ float scs[256];
    const int g = blockIdx.x, ic = blockIdx.y, tid = threadIdx.x;
    scs[tid] = sc[(size_t)g * LA + ic * 256 + tid];
    __syncthreads();
    const __hip_bfloat16* Xg = X + ((size_t)g * LA + ic * 256) * HDIM + tid * 4;
    float a0 = 0.f, a1 = 0.f, a2 = 0.f, a3 = 0.f;
    for (int i = 0; i < 256; i++){
        short4 v = *(const short4*)(Xg + (size_t)i * HDIM);
        float w = scs[i];
        a0 = fmaf(w, __bfloat162float(*(const __hip_bfloat16*)&v.x), a0);
        a1 = fmaf(w, __bfloat162float(*(const __hip_bfloat16*)&v.y), a1);
        a2 = fmaf(w, __bfloat162float(*(const __hip_bfloat16*)&v.z), a2);
        a3 = fmaf(w, __bfloat162float(*(const __hip_bfloat16*)&v.w), a3);
    }
    float* o = out + (size_t)g * HDIM + tid * 4;
    atomicAdd(o + 0, a0); atomicAdd(o + 1, a1);
    atomicAdd(o + 2, a2); atomicAdd(o + 3, a3);
}

// vectorized bf16 weighted sum (options): grid 160, direct store (no atomics)
__global__ __launch_bounds__(256) void wsum_opt_v(
    const __hip_bfloat16* __restrict__ X, const float* __restrict__ sc,
    float* __restrict__ out){
    __shared__ float scs[LO];
    const int g = blockIdx.x, tid = threadIdx.x;
    if (tid < LO) scs[tid] = sc[(size_t)g * LO + tid];
    __syncthreads();
    const __hip_bfloat16* Xg = X + (size_t)g * LO * HDIM + tid * 4;
    float a0 = 0.f, a1 = 0.f, a2 = 0.f, a3 = 0.f;
    for (int i = 0; i < LO; i++){
        short4 v = *(const short4*)(Xg + (size_t)i * HDIM);
        float w = scs[i];
        a0 = fmaf(w, __bfloat162float(*(const __hip_bfloat16*)&v.x), a0);
        a1 = fmaf(w, __bfloat162float(*(const __hip_bfloat16*)&v.y), a1);
        a2 = fmaf(w, __bfloat162float(*(const __hip_bfloat16*)&v.z), a2);
        a3 = fmaf(w, __bfloat162float(*(const __hip_bfloat16*)&v.w), a3);
    }
    float* o = out + (size_t)g * HDIM + tid * 4;
    o[0] = a0; o[1] = a1; o[2] = a2; o[3] = a3;
}

// logits[b,j] = fb[j] + dot(feats[b,:5120], fw[j,:5120])  grid 32, block 256
__global__ void final_kernel(const float* __restrict__ feats, const float* __restrict__ fw,
                             const float* __restrict__ fb, float* __restrict__ out){
    __shared__ float red[4];
    int b = blockIdx.x, tid = threadIdx.x;
    const float* fe = feats + (size_t)b * 5120;
    for (int j = 0; j < 5; j++){
        float acc = 0.f;
        for (int i = tid; i < 5120; i += 256) acc += fe[i] * fw[(size_t)j * 5120 + i];
        #pragma unroll
        for (int off = 32; off > 0; off >>= 1) acc += __shfl_down(acc, off, 64);
        if ((tid & 63) == 0) red[tid >> 6] = acc;
        __syncthreads();
        if (tid == 0) out[b * 5 + j] = fb[j] + red[0] + red[1] + red[2] + red[3];
        __syncthreads();
    }
}

extern "C" void kernel_launch(void* const* d_in, const int* in_sizes, int n_in,
                              void* d_out, int out_size, void* d_ws, size_t ws_size,
                              hipStream_t stream) {
    const float* article  = (const float*)d_in[0];
    const float* question = (const float*)d_in[1];
    const float* options  = (const float*)d_in[2];
    const int*   ans      = (const int*)d_in[3];
    const float* a_Qw = (const float*)d_in[4];  const float* a_Qb = (const float*)d_in[5];
    const float* a_Kw = (const float*)d_in[6];  const float* a_Kb = (const float*)d_in[7];
    const float* a_Vw = (const float*)d_in[8];  const float* a_Vb = (const float*)d_in[9];
    const float* a_vw = (const float*)d_in[10];
    const float* d_Qw = (const float*)d_in[12]; const float* d_Qb = (const float*)d_in[13];
    const float* d_Kw = (const float*)d_in[14]; const float* d_Kb = (const float*)d_in[15];
    const float* d_Vw = (const float*)d_in[16]; const float* d_Vb = (const float*)d_in[17];
    const float* d_vw = (const float*)d_in[18];
    const float* f_w  = (const float*)d_in[20]; const float* f_b  = (const float*)d_in[21];
    float* out = (float*)d_out;

    float* ws = (float*)d_ws;
    float* qp_a  = ws + 32768;       // 32768
    float* aq    = ws + 65536;       // 32768
    float* qp_d  = ws + 98304;       // 32768
    float* feats = ws + 131072;      // 163840
    float* s_art = ws + 294912;      // 65536  (zeroed)
    float* s_opt = ws + 360448;      // 5120   (zeroed)
    float* w_art = ws + 365568;      // 32768  (zeroed)
    float* wd    = ws + 398336;      // 163840 (direct-store, no zero)
    // bf16 region
    __hip_bfloat16* kwa_bf = (__hip_bfloat16*)(ws + 562176);
    __hip_bfloat16* kwd_bf = kwa_bf + 1048576;
    __hip_bfloat16* opt_bf = kwd_bf + 1048576;       // 5242880 elems
    __hip_bfloat16* art_bf = opt_bf + 5242880;       // 67108864 elems

    // zero s_art + s_opt + w_art (contiguous: 65536+5120+32768 = 103424)
    zero_kernel<<<128, 256, 0, stream>>>(s_art, 103424);
    proj_q_kernel<<<dim3(NB, 16), 256, 0, stream>>>(question, ans, a_Qw, a_Qb, qp_a);
    conv_bf16_kernel<<<64, 256, 0, stream>>>(a_Kw, kwa_bf, 1048576);
    conv_bf16_kernel<<<1024, 256, 0, stream>>>(article, art_bf, (long)NB * LA * HDIM);

    score_mfma8p<<<(NB * LA / 256) * 4, 512, 0, stream>>>(
        art_bf, kwa_bf, a_Kb, qp_a, a_vw, s_art, LA);
    softmax_kernel<<<NB, 256, 0, stream>>>(s_art, LA);
    wsum_art_v<<<dim3(NB, 8), 256, 0, stream>>>(art_bf, s_art, w_art);
    proj_kernel<<<dim3(NB, 16), 256, 0, stream>>>(w_art, a_Vw, a_Vb, aq);

    proj_kernel<<<dim3(NB, 16), 256, 0, stream>>>(aq, d_Qw, d_Qb, qp_d);
    conv2_bf16_kernel<<<384, 256, 0, stream>>>(d_Kw, kwd_bf, 1048576,
                                               options, opt_bf, 5242880);
    score_mfma_kernel<<<dim3((NB * 5 * LO) / SBM, HDIM / SBN), 256, 0, stream>>>(
        opt_bf, kwd_bf, d_Kb, qp_d, d_vw, s_opt, 0, 5 * LO);
    softmax_kernel<<<NB * 5, 256, 0, stream>>>(s_opt, LO);
    wsum_opt_v<<<NB * 5, 256, 0, stream>>>(opt_bf, s_opt, wd);
    proj_kernel<<<dim3(NB * 5, 16), 256, 0, stream>>>(wd, d_Vw, d_Vb, feats);
    final_kernel<<<NB, 256, 0, stream>>>(feats, f_w, f_b, out);
}